// Round 6
// baseline (279.503 us; speedup 1.0000x reference)
//
#include <hip/hip_runtime.h>

#define BATCH 64
#define TLEN  512
#define HDIM  768
#define LTAGS 9

// Workspace layout (bytes)
#define WS_LOGD 0                        // f64 [32768][9]   = 2359296
#define WS_LOGF 2359296                  // f32 [32768][9]   = 1179648
#define WS_LOSS 3538944                  // f64 [64]         = 512
#define WS_CNT  3539456                  // u32 [1]

// ---------------------------------------------------------------------------
// Kernel A: logits = hidden @ W^T + b.  f32 dot4 segments accumulated in f64.
// (unchanged numerics; additionally zero-inits the loss ticket counter)
// ---------------------------------------------------------------------------
__global__ __launch_bounds__(256) void logits_kernel(
    const float* __restrict__ hidden, const float* __restrict__ W,
    const float* __restrict__ bvec, double* __restrict__ logitsD,
    float* __restrict__ logitsF, unsigned int* __restrict__ wsCnt)
{
    __shared__ float sW[LTAGS * HDIM];
    __shared__ float sb[LTAGS];
    const int tid = threadIdx.x;
    if (blockIdx.x == 0 && tid == 0) *wsCnt = 0u;
    for (int i = tid; i < LTAGS * HDIM; i += 256) sW[i] = W[i];
    if (tid < LTAGS) sb[tid] = bvec[tid];
    __syncthreads();

    const int lane = tid & 63;
    const int wave = tid >> 6;
    const int sub  = lane & 7;
    const int rg   = lane >> 3;

    const int rowBase = blockIdx.x * 64 + wave * 16;
    const int r0 = rowBase + rg;
    const int r1 = rowBase + rg + 8;
    const float* h0p = hidden + (size_t)r0 * HDIM;
    const float* h1p = hidden + (size_t)r1 * HDIM;

    double acc0[LTAGS], acc1[LTAGS];
    #pragma unroll
    for (int l = 0; l < LTAGS; ++l) { acc0[l] = 0.0; acc1[l] = 0.0; }

    #pragma unroll 2
    for (int i = 0; i < 24; ++i) {
        const int off = i * 32 + sub * 4;
        const float4 h0 = *(const float4*)(h0p + off);
        const float4 h1 = *(const float4*)(h1p + off);
        #pragma unroll
        for (int l = 0; l < LTAGS; ++l) {
            const float4 w = *(const float4*)&sW[l * HDIM + off];
            float d0 = h0.x * w.x;
            d0 = fmaf(h0.y, w.y, d0); d0 = fmaf(h0.z, w.z, d0); d0 = fmaf(h0.w, w.w, d0);
            float d1 = h1.x * w.x;
            d1 = fmaf(h1.y, w.y, d1); d1 = fmaf(h1.z, w.z, d1); d1 = fmaf(h1.w, w.w, d1);
            acc0[l] += (double)d0;
            acc1[l] += (double)d1;
        }
    }
    #pragma unroll
    for (int l = 0; l < LTAGS; ++l) {
        double v0 = acc0[l], v1 = acc1[l];
        #pragma unroll
        for (int off = 4; off > 0; off >>= 1) {
            v0 += __shfl_down(v0, off);
            v1 += __shfl_down(v1, off);
        }
        acc0[l] = v0; acc1[l] = v1;
    }
    if (sub == 0) {
        #pragma unroll
        for (int l = 0; l < LTAGS; ++l) {
            double v0 = acc0[l] + (double)sb[l];
            double v1 = acc1[l] + (double)sb[l];
            logitsD[(size_t)r0 * LTAGS + l] = v0;
            logitsD[(size_t)r1 * LTAGS + l] = v1;
            logitsF[(size_t)r0 * LTAGS + l] = (float)v0;
            logitsF[(size_t)r1 * LTAGS + l] = (float)v1;
        }
    }
}

// ---------------------------------------------------------------------------
// Fused CRF kernel: 128 blocks x 576 threads.
// Register diet: the backend caps this kernel at 84 VGPRs (6 waves/EU
// heuristic; launch_bounds(,1) is only a *minimum* and does not lift it).
// Peak live state per phase is kept under that cap:
//   - phase-1 loops: no lg[9] array; lgv loaded per-j where consumed
//     (peak = M[9]+nw[9] = 36 f64 = 72 VGPRs, was 54 f64 = 108 -> spilled)
//   - boundary scans: no Mn[9]/g[9]; LDS reads + shfl folded into the chain
// FP values and op order identical to the verified version -> absmax 0.
// ---------------------------------------------------------------------------
__global__ __launch_bounds__(576, 1) void crf_fused(
    const float* __restrict__ trans, const int* __restrict__ labels,
    const int* __restrict__ att, const double* __restrict__ logitsD,
    const float* __restrict__ logitsF, double* __restrict__ wsLoss,
    unsigned int* __restrict__ wsCnt, float* __restrict__ out)
{
    __shared__ __align__(16) double sVM[64 * 81];       // 41472 B
    __shared__ __align__(16) float  sAM[32 * 81];       // 10368 B
    __shared__ double sVstart[65 * LTAGS];              // 4680 B
    __shared__ unsigned char sBPb[513 * 16];            // 8208 B
    __shared__ double sT64[81];
    __shared__ float  sE32[81];
    __shared__ unsigned char sMk[TLEN + 1];
    __shared__ int sTagB[65];
    __shared__ double sDen, sNum;
    __shared__ int sLast;
    __shared__ unsigned int sTicket;

    const int tid  = threadIdx.x;
    const int wave = tid >> 6, lane = tid & 63;
    const int blk  = blockIdx.x;
    const bool isVit = (blk < BATCH);
    const int b = isVit ? blk : (blk - BATCH);

    if (tid < 81) { float tv = trans[tid]; sT64[tid] = (double)tv; sE32[tid] = __expf(tv); }
    const int* lab = labels + b * TLEN;
    const int* am  = att + b * TLEN;
    for (int t = tid; t < TLEN; t += 576)
        sMk[t] = (am[t] != 0 && lab[t] != -100) ? 1 : 0;
    if (tid == 0) sMk[TLEN] = 0;
    __syncthreads();

    if (isVit) {
        // ---- phase 1: 576 chunk-matrix rows, one per thread, into LDS ----
        {
            const int c = tid / 9;
            const int i = tid - c * 9;
            double M[LTAGS];
            #pragma unroll
            for (int j = 0; j < LTAGS; ++j) M[j] = (i == j) ? 0.0 : -1e300;

            const double* lrow = logitsD + ((size_t)b * TLEN + (c * 8 + 1)) * LTAGS;
            const int t0 = c * 8 + 1;

            for (int s = 0; s < 8; ++s) {
                const int t = t0 + s;
                const bool mk = sMk[t] != 0;   // sMk[512]==0 masks the tail
                double nw[LTAGS];
                #pragma unroll
                for (int j = 0; j < LTAGS; ++j) {
                    double bst = M[0] + sT64[j];
                    #pragma unroll
                    for (int k = 1; k < LTAGS; ++k) {
                        double cnd = M[k] + sT64[k * LTAGS + j];
                        bst = fmax(bst, cnd);
                    }
                    double lgv = (t < TLEN) ? lrow[s * LTAGS + j] : 0.0;
                    nw[j] = bst + lgv;
                }
                #pragma unroll
                for (int j = 0; j < LTAGS; ++j) M[j] = mk ? nw[j] : M[j];
            }
            double* dst = &sVM[(c * LTAGS + i) * LTAGS];
            #pragma unroll
            for (int j = 0; j < LTAGS; ++j) dst[j] = M[j];
        }
        __syncthreads();

        // ---- phase 2: serial boundary scan over 64 chunk matrices (wave0) ----
        if (wave == 0) {
            const int j = (lane < LTAGS) ? lane : (LTAGS - 1);
            double v = logitsD[(size_t)b * TLEN * LTAGS + j];
            for (int c = 0; c < 64; ++c) {
                if (lane < LTAGS) sVstart[c * LTAGS + j] = v;
                double bst = __shfl(v, 0) + sVM[c * 81 + j];
                #pragma unroll
                for (int i = 1; i < LTAGS; ++i) {
                    double cand = __shfl(v, i) + sVM[c * 81 + i * LTAGS + j];
                    bst = fmax(bst, cand);
                }
                v = bst;
            }
            if (lane < LTAGS) sVstart[64 * LTAGS + j] = v;
            double g[LTAGS];
            #pragma unroll
            for (int i = 0; i < LTAGS; ++i) g[i] = __shfl(v, i);
            if (lane == 0) {
                int bi = 0; double bv = g[0];
                #pragma unroll
                for (int i = 1; i < LTAGS; ++i) if (g[i] > bv) { bv = g[i]; bi = i; }
                sLast = bi;
            }
        }
        __syncthreads();

        // ---- phase 3: replay, 9x parallel (16-lane groups, 2 passes) ----
        {
            const int grp = tid >> 4;                 // 0..35
            const int lig = tid & 15;
            const int jr = (lig < 9) ? lig : 8;
            const int gbase = lane & 48;              // 16-group base within wave
            for (int pass = 0; pass < 2; ++pass) {
                const int c = pass * 36 + grp;
                if (c < 64) {
                    double v = sVstart[c * LTAGS + jr];
                    const double* lrow = logitsD + ((size_t)b * TLEN + (c * 8 + 1)) * LTAGS;
                    for (int s = 0; s < 8; ++s) {
                        const int t = c * 8 + 1 + s;
                        double lgv = 0.0;
                        if (t < TLEN) lgv = lrow[s * LTAGS + jr];
                        const bool mk = sMk[t] != 0;
                        double g0 = __shfl(v, gbase + 0);
                        double bst = g0 + sT64[jr];
                        int bi = 0;
                        #pragma unroll
                        for (int k = 1; k < LTAGS; ++k) {
                            double gk = __shfl(v, gbase + k);
                            double cnd = gk + sT64[k * LTAGS + jr];
                            bool gt = cnd > bst;
                            bst = gt ? cnd : bst;
                            bi  = gt ? k : bi;
                        }
                        double nv = bst + lgv;
                        int bp = mk ? bi : jr;
                        if (lig < 9) sBPb[t * 16 + lig] = (unsigned char)bp;
                        v = mk ? nv : v;
                    }
                }
            }
        }
        __syncthreads();

        // ---- phase 4: per-chunk composed maps + suffix composition scan ----
        if (tid < 64) {
            int Gm[LTAGS];
            #pragma unroll
            for (int j = 0; j < LTAGS; ++j) Gm[j] = j;
            for (int s = 7; s >= 0; --s) {
                const int t = tid * 8 + 1 + s;
                #pragma unroll
                for (int j = 0; j < LTAGS; ++j) Gm[j] = sBPb[t * 16 + Gm[j]];
            }
            unsigned long long S = 0;
            #pragma unroll
            for (int j = 0; j < LTAGS; ++j) S |= ((unsigned long long)Gm[j]) << (4 * j);

            #pragma unroll
            for (int d = 1; d < 64; d <<= 1) {
                unsigned long long Sn = __shfl_down(S, d);
                if (lane + d < 64) {
                    unsigned long long R = 0;
                    #pragma unroll
                    for (int x = 0; x < LTAGS; ++x) {
                        int y = (int)((Sn >> (4 * x)) & 15);
                        int z = (int)((S >> (4 * y)) & 15);
                        R |= ((unsigned long long)z) << (4 * x);
                    }
                    S = R;
                }
            }
            const int lt = sLast;
            sTagB[tid] = (int)((S >> (4 * lt)) & 15);
            if (tid == 0) sTagB[64] = lt;
        }
        __syncthreads();

        // ---- phase 5: chunk-parallel expansion -> predictions ----
        if (tid < 64) {
            const int c = tid;
            int cur = sTagB[c + 1];
            float* po = out + 1 + b * TLEN;
            for (int s = 8; s >= 1; --s) {
                const int t = c * 8 + s;
                if (t < TLEN) {
                    int nxt = (int)sBPb[t * 16 + cur];
                    po[t] = sMk[t - 1] ? (float)nxt : -100.f;
                    cur = nxt;
                }
            }
        }
        if (tid == 0) out[1 + b * TLEN] = -100.f;
    } else {
        // ======================= alpha / loss block =======================
        if (tid < 288) {
            // ---- phase 1: 288 alpha chunk rows into LDS ----
            const int c = tid / 9;
            const int i = tid - c * 9;
            float M[LTAGS];
            #pragma unroll
            for (int j = 0; j < LTAGS; ++j) M[j] = (i == j) ? 0.f : -1e30f;

            const float* lrow = logitsF + ((size_t)b * TLEN + (c * 16 + 1)) * LTAGS;
            const int t0 = c * 16 + 1;

            for (int s = 0; s < 16; ++s) {
                const int t = t0 + s;
                const bool mk = sMk[t] != 0;
                float m = M[0];
                #pragma unroll
                for (int k = 1; k < LTAGS; ++k) m = fmaxf(m, M[k]);
                float P[LTAGS];
                #pragma unroll
                for (int k = 0; k < LTAGS; ++k) P[k] = __expf(M[k] - m);
                float nw[LTAGS];
                #pragma unroll
                for (int j = 0; j < LTAGS; ++j) {
                    float sacc = P[0] * sE32[j];
                    #pragma unroll
                    for (int k = 1; k < LTAGS; ++k) sacc = fmaf(P[k], sE32[k * LTAGS + j], sacc);
                    float lgv = (t < TLEN) ? lrow[s * LTAGS + j] : 0.f;
                    nw[j] = m + __logf(sacc) + lgv;
                }
                #pragma unroll
                for (int j = 0; j < LTAGS; ++j) M[j] = mk ? nw[j] : M[j];
            }
            float* dst = &sAM[(c * LTAGS + i) * LTAGS];
            #pragma unroll
            for (int j = 0; j < LTAGS; ++j) dst[j] = M[j];
        } else if (tid >= 512) {
            // ---- numerator: wave 8, identical op order to previous version ----
            const double* lrowb = logitsD + (size_t)b * TLEN * LTAGS;
            double part = 0.0;
            #pragma unroll
            for (int k = 0; k < 8; ++k) {
                const int t = lane + k * 64;
                int lv = lab[t], av = am[t];
                bool mkc = (av != 0) && (lv != -100);
                int tg = (lv == -100) ? 0 : lv;
                if (mkc) part += lrowb[(size_t)t * LTAGS + tg];
                if (t < TLEN - 1) {
                    int lv2 = lab[t + 1], av2 = am[t + 1];
                    bool mk2 = (av2 != 0) && (lv2 != -100);
                    int tg2 = (lv2 == -100) ? 0 : lv2;
                    if (mk2) part += sT64[tg * LTAGS + tg2];
                }
            }
            #pragma unroll
            for (int off = 32; off > 0; off >>= 1) part += __shfl_down(part, off);
            if (lane == 0) sNum = part;
        }
        __syncthreads();

        // ---- serial alpha boundary scan over 32 chunk matrices (wave0) ----
        if (wave == 0) {
            const int j = (lane < LTAGS) ? lane : (LTAGS - 1);
            float v = (float)logitsD[(size_t)b * TLEN * LTAGS + j];
            for (int c = 0; c < 32; ++c) {
                float a[LTAGS];
                #pragma unroll
                for (int i = 0; i < LTAGS; ++i)
                    a[i] = __shfl(v, i) + sAM[c * 81 + i * LTAGS + j];
                float m = a[0];
                #pragma unroll
                for (int i = 1; i < LTAGS; ++i) m = fmaxf(m, a[i]);
                float sacc = 0.f;
                #pragma unroll
                for (int i = 0; i < LTAGS; ++i) sacc += __expf(a[i] - m);
                v = m + __logf(sacc);
            }
            float g[LTAGS];
            #pragma unroll
            for (int i = 0; i < LTAGS; ++i) g[i] = __shfl(v, i);
            if (lane == 0) {
                float m = g[0];
                #pragma unroll
                for (int i = 1; i < LTAGS; ++i) m = fmaxf(m, g[i]);
                float sacc = 0.f;
                #pragma unroll
                for (int i = 0; i < LTAGS; ++i) sacc += __expf(g[i] - m);
                sDen = (double)(m + __logf(sacc));
            }
        }
        __syncthreads();

        // ---- per-batch loss + last-block reduction (bit-identical tree) ----
        if (tid == 0) {
            wsLoss[b] = sDen - sNum;
            __threadfence();
            sTicket = atomicAdd(wsCnt, 1u);
        }
        __syncthreads();
        if (sTicket == (BATCH - 1)) {
            __threadfence();
            if (tid < 64) {
                double v = wsLoss[tid];
                #pragma unroll
                for (int off = 32; off > 0; off >>= 1) v += __shfl_down(v, off);
                if (tid == 0) out[0] = (float)v;
            }
        }
    }
}

extern "C" void kernel_launch(void* const* d_in, const int* in_sizes, int n_in,
                              void* d_out, int out_size, void* d_ws, size_t ws_size,
                              hipStream_t stream)
{
    const float* hidden = (const float*)d_in[0];
    const float* W      = (const float*)d_in[1];
    const float* bvec   = (const float*)d_in[2];
    const float* trans  = (const float*)d_in[3];
    const int*   labels = (const int*)d_in[4];
    const int*   att    = (const int*)d_in[5];
    float* out = (float*)d_out;

    char* ws = (char*)d_ws;
    double* logitsD = (double*)(ws + WS_LOGD);
    float*  logitsF = (float*)(ws + WS_LOGF);
    double* wsLoss  = (double*)(ws + WS_LOSS);
    unsigned int* wsCnt = (unsigned int*)(ws + WS_CNT);

    logits_kernel<<<512, 256, 0, stream>>>(hidden, W, bvec, logitsD, logitsF, wsCnt);
    crf_fused<<<2 * BATCH, 576, 0, stream>>>(trans, labels, att, logitsD, logitsF,
                                             wsLoss, wsCnt, out);
}

// Round 10
// 217.917 us; speedup vs baseline: 1.2826x; 1.2826x over previous
//
#include <hip/hip_runtime.h>

#define BATCH 64
#define TLEN  512
#define HDIM  768
#define LTAGS 9

// Workspace layout (bytes)
#define WS_LOGD 0                        // f64 [32768][9]   = 2359296
#define WS_LOGF 2359296                  // f32 [32768][9]   = 1179648
#define WS_VM   3538944                  // f64 [64][64][9][9] = 2654208
#define WS_AM   6193152                  // f32 [64][32][9][9] = 663552
#define WS_NUM  6856704                  // f64 [64]
#define WS_LOSS 6857216                  // f64 [64]
#define WS_CNT  6857728                  // u32 [1]

// ---------------------------------------------------------------------------
// Kernel A: logits = hidden @ W^T + b.  f32 dot4 segments accumulated in f64.
// (round-0 verified version + wsCnt zero-init for the loss ticket)
// ---------------------------------------------------------------------------
__global__ __launch_bounds__(256) void logits_kernel(
    const float* __restrict__ hidden, const float* __restrict__ W,
    const float* __restrict__ bvec, double* __restrict__ logitsD,
    float* __restrict__ logitsF, unsigned int* __restrict__ wsCnt)
{
    __shared__ float sW[LTAGS * HDIM];
    __shared__ float sb[LTAGS];
    const int tid = threadIdx.x;
    if (blockIdx.x == 0 && tid == 0) *wsCnt = 0u;
    for (int i = tid; i < LTAGS * HDIM; i += 256) sW[i] = W[i];
    if (tid < LTAGS) sb[tid] = bvec[tid];
    __syncthreads();

    const int lane = tid & 63;
    const int wave = tid >> 6;
    const int sub  = lane & 7;
    const int rg   = lane >> 3;

    const int rowBase = blockIdx.x * 64 + wave * 16;
    const int r0 = rowBase + rg;
    const int r1 = rowBase + rg + 8;
    const float* h0p = hidden + (size_t)r0 * HDIM;
    const float* h1p = hidden + (size_t)r1 * HDIM;

    double acc0[LTAGS], acc1[LTAGS];
    #pragma unroll
    for (int l = 0; l < LTAGS; ++l) { acc0[l] = 0.0; acc1[l] = 0.0; }

    #pragma unroll 2
    for (int i = 0; i < 24; ++i) {
        const int off = i * 32 + sub * 4;
        const float4 h0 = *(const float4*)(h0p + off);
        const float4 h1 = *(const float4*)(h1p + off);
        #pragma unroll
        for (int l = 0; l < LTAGS; ++l) {
            const float4 w = *(const float4*)&sW[l * HDIM + off];
            float d0 = h0.x * w.x;
            d0 = fmaf(h0.y, w.y, d0); d0 = fmaf(h0.z, w.z, d0); d0 = fmaf(h0.w, w.w, d0);
            float d1 = h1.x * w.x;
            d1 = fmaf(h1.y, w.y, d1); d1 = fmaf(h1.z, w.z, d1); d1 = fmaf(h1.w, w.w, d1);
            acc0[l] += (double)d0;
            acc1[l] += (double)d1;
        }
    }
    #pragma unroll
    for (int l = 0; l < LTAGS; ++l) {
        double v0 = acc0[l], v1 = acc1[l];
        #pragma unroll
        for (int off = 4; off > 0; off >>= 1) {
            v0 += __shfl_down(v0, off);
            v1 += __shfl_down(v1, off);
        }
        acc0[l] = v0; acc1[l] = v1;
    }
    if (sub == 0) {
        #pragma unroll
        for (int l = 0; l < LTAGS; ++l) {
            double v0 = acc0[l] + (double)sb[l];
            double v1 = acc1[l] + (double)sb[l];
            logitsD[(size_t)r0 * LTAGS + l] = v0;
            logitsD[(size_t)r1 * LTAGS + l] = v1;
            logitsF[(size_t)r0 * LTAGS + l] = (float)v0;
            logitsF[(size_t)r1 * LTAGS + l] = (float)v1;
        }
    }
}

// ---------------------------------------------------------------------------
// Kernel B1 (chunk): 232 blocks x 256 threads.  (round-0 verified version)
//   blocks [0,144):   Viterbi chunk-matrix rows (b,c,i), f64 max-plus, 8 steps
//   blocks [144,216): alpha chunk-matrix rows (b,c,i), f32 log-plus, 16 steps
//   blocks [216,232): numerator, one wave per batch
// ---------------------------------------------------------------------------
__global__ __launch_bounds__(256) void chunk_kernel(
    const float* __restrict__ trans, const int* __restrict__ labels,
    const int* __restrict__ att, const double* __restrict__ logitsD,
    const float* __restrict__ logitsF,
    double* __restrict__ wsVM, float* __restrict__ wsAM,
    double* __restrict__ wsNum)
{
    __shared__ double sT64[81];
    __shared__ float  sE32[81];
    const int tid = threadIdx.x;
    if (tid < 81) { float tv = trans[tid]; sT64[tid] = (double)tv; sE32[tid] = __expf(tv); }
    __syncthreads();

    const int blk = blockIdx.x;
    if (blk < 144) {
        // ---- Viterbi chunk rows ----
        const int gid = blk * 256 + tid;          // 0..36863
        const int b   = gid / 576;
        const int rem = gid - b * 576;
        const int c   = rem / 9;
        const int i   = rem - c * 9;

        double M[LTAGS];
        #pragma unroll
        for (int j = 0; j < LTAGS; ++j) M[j] = (i == j) ? 0.0 : -1e300;

        const double* lrow = logitsD + ((size_t)b * TLEN + (c * 8 + 1)) * LTAGS;
        const int* lab = labels + b * TLEN;
        const int* am  = att + b * TLEN;
        const int t0 = c * 8 + 1;

        double lg[LTAGS], lgN[LTAGS];
        #pragma unroll
        for (int j = 0; j < LTAGS; ++j) lg[j] = lrow[j];
        bool mk = (am[t0] != 0) && (lab[t0] != -100);

        for (int s = 0; s < 8; ++s) {
            bool mkN = false;
            const int tn = t0 + s + 1;
            if (s < 7 && tn <= TLEN - 1) {
                const double* ln = lrow + (s + 1) * LTAGS;
                #pragma unroll
                for (int j = 0; j < LTAGS; ++j) lgN[j] = ln[j];
                mkN = (am[tn] != 0) && (lab[tn] != -100);
            }
            double nw[LTAGS];
            #pragma unroll
            for (int j = 0; j < LTAGS; ++j) {
                double bst = M[0] + sT64[j];
                #pragma unroll
                for (int k = 1; k < LTAGS; ++k) {
                    double cnd = M[k] + sT64[k * LTAGS + j];
                    bst = fmax(bst, cnd);
                }
                nw[j] = bst + lg[j];
            }
            #pragma unroll
            for (int j = 0; j < LTAGS; ++j) { M[j] = mk ? nw[j] : M[j]; lg[j] = lgN[j]; }
            mk = mkN;
        }
        double* dst = wsVM + (((size_t)b * 64 + c) * LTAGS + i) * LTAGS;
        #pragma unroll
        for (int j = 0; j < LTAGS; ++j) dst[j] = M[j];
    } else if (blk < 216) {
        // ---- alpha chunk rows ----
        const int gid = (blk - 144) * 256 + tid;  // 0..18431
        const int b   = gid / 288;
        const int rem = gid - b * 288;
        const int c   = rem / 9;
        const int i   = rem - c * 9;

        float M[LTAGS];
        #pragma unroll
        for (int j = 0; j < LTAGS; ++j) M[j] = (i == j) ? 0.f : -1e30f;

        const float* lrow = logitsF + ((size_t)b * TLEN + (c * 16 + 1)) * LTAGS;
        const int* lab = labels + b * TLEN;
        const int* am  = att + b * TLEN;
        const int t0 = c * 16 + 1;

        float lg[LTAGS], lgN[LTAGS];
        #pragma unroll
        for (int j = 0; j < LTAGS; ++j) lg[j] = lrow[j];
        bool mk = (am[t0] != 0) && (lab[t0] != -100);

        for (int s = 0; s < 16; ++s) {
            bool mkN = false;
            const int tn = t0 + s + 1;
            if (s < 15 && tn <= TLEN - 1) {
                const float* ln = lrow + (s + 1) * LTAGS;
                #pragma unroll
                for (int j = 0; j < LTAGS; ++j) lgN[j] = ln[j];
                mkN = (am[tn] != 0) && (lab[tn] != -100);
            }
            float m = M[0];
            #pragma unroll
            for (int k = 1; k < LTAGS; ++k) m = fmaxf(m, M[k]);
            float P[LTAGS];
            #pragma unroll
            for (int k = 0; k < LTAGS; ++k) P[k] = __expf(M[k] - m);
            float nw[LTAGS];
            #pragma unroll
            for (int j = 0; j < LTAGS; ++j) {
                float sacc = P[0] * sE32[j];
                #pragma unroll
                for (int k = 1; k < LTAGS; ++k) sacc = fmaf(P[k], sE32[k * LTAGS + j], sacc);
                nw[j] = m + __logf(sacc) + lg[j];
            }
            #pragma unroll
            for (int j = 0; j < LTAGS; ++j) { M[j] = mk ? nw[j] : M[j]; lg[j] = lgN[j]; }
            mk = mkN;
        }
        float* dst = wsAM + (((size_t)b * 32 + c) * LTAGS + i) * LTAGS;
        #pragma unroll
        for (int j = 0; j < LTAGS; ++j) dst[j] = M[j];
    } else {
        // ---- numerator: one wave per batch ----
        const int bb   = (blk - 216) * 4 + (tid >> 6);
        const int lane = tid & 63;
        const int* lab = labels + bb * TLEN;
        const int* am  = att + bb * TLEN;
        const double* lrowb = logitsD + (size_t)bb * TLEN * LTAGS;
        double part = 0.0;
        #pragma unroll
        for (int k = 0; k < 8; ++k) {
            const int t = lane + k * 64;
            int lv = lab[t], av = am[t];
            bool mkc = (av != 0) && (lv != -100);
            int tg = (lv == -100) ? 0 : lv;
            if (mkc) part += lrowb[(size_t)t * LTAGS + tg];
            if (t < TLEN - 1) {
                int lv2 = lab[t + 1], av2 = am[t + 1];
                bool mk2 = (av2 != 0) && (lv2 != -100);
                int tg2 = (lv2 == -100) ? 0 : lv2;
                if (mk2) part += sT64[tg * LTAGS + tg2];
            }
        }
        #pragma unroll
        for (int off = 32; off > 0; off >>= 1) part += __shfl_down(part, off);
        if (lane == 0) wsNum[bb] = part;
    }
}

// ---------------------------------------------------------------------------
// Kernel B2 (crf2): per-batch block, 128 threads.  (round-0 verified version
// + ticket-counter loss fold: last block re-runs loss_kernel's exact 64-lane
// shfl tree -> bit-identical loss, one fewer launch)
// ---------------------------------------------------------------------------
__global__ __launch_bounds__(128) void crf2_kernel(
    const float* __restrict__ trans, const int* __restrict__ labels,
    const int* __restrict__ att, const double* __restrict__ logitsD,
    const double* __restrict__ wsVM, const float* __restrict__ wsAM,
    const double* __restrict__ wsNum, double* __restrict__ wsLoss,
    unsigned int* __restrict__ wsCnt, float* __restrict__ out)
{
    __shared__ __align__(16) double sVM[64 * 81];     // 41472 B
    __shared__ __align__(16) float  sAM[32 * 81];     // 10368 B
    __shared__ double sVstart[65 * LTAGS];            // 4680 B
    __shared__ unsigned long long sBPp[513];          // 4104 B
    __shared__ int sTagB[65];
    __shared__ double sT64[81];
    __shared__ unsigned char sMk[513];
    __shared__ double sDen;
    __shared__ int sLast;
    __shared__ unsigned int sTicket;

    const int b = blockIdx.x, tid = threadIdx.x;
    const int wave = tid >> 6, lane = tid & 63;
    const unsigned long long IDMAP = 0x876543210ull;

    // ---- stage chunk matrices + masks into LDS (coalesced) ----
    const double2* gVM = (const double2*)(wsVM + (size_t)b * 64 * 81);
    double2* sVM2 = (double2*)sVM;
    for (int i = tid; i < 2592; i += 128) sVM2[i] = gVM[i];
    const float4* gAM = (const float4*)(wsAM + (size_t)b * 32 * 81);
    float4* sAM4 = (float4*)sAM;
    for (int i = tid; i < 648; i += 128) sAM4[i] = gAM[i];

    const int* lab = labels + b * TLEN;
    const int* am  = att + b * TLEN;
    for (int t = tid; t < TLEN; t += 128) {
        int lv = lab[t], av = am[t];
        sMk[t] = (av != 0 && lv != -100) ? 1 : 0;
    }
    if (tid == 0) sMk[TLEN] = 0;
    if (tid < 81) sT64[tid] = (double)trans[tid];
    __syncthreads();

    if (wave == 0) {
        // ---- Viterbi boundary scan over 64 chunk matrices (LDS) ----
        const int j = (lane < LTAGS) ? lane : (LTAGS - 1);
        double v = logitsD[(size_t)b * TLEN * LTAGS + j];
        double Mc[LTAGS], Mn[LTAGS];
        #pragma unroll
        for (int i = 0; i < LTAGS; ++i) Mc[i] = sVM[i * LTAGS + j];
        for (int c = 0; c < 64; ++c) {
            if (c < 63) {
                #pragma unroll
                for (int i = 0; i < LTAGS; ++i) Mn[i] = sVM[(c + 1) * 81 + i * LTAGS + j];
            }
            if (lane < LTAGS) sVstart[c * LTAGS + j] = v;
            double g[LTAGS];
            #pragma unroll
            for (int i = 0; i < LTAGS; ++i) g[i] = __shfl(v, i);
            double bst = g[0] + Mc[0];
            #pragma unroll
            for (int i = 1; i < LTAGS; ++i) bst = fmax(bst, g[i] + Mc[i]);
            v = bst;
            if (c < 63) {
                #pragma unroll
                for (int i = 0; i < LTAGS; ++i) Mc[i] = Mn[i];
            }
        }
        if (lane < LTAGS) sVstart[64 * LTAGS + j] = v;
        double g[LTAGS];
        #pragma unroll
        for (int i = 0; i < LTAGS; ++i) g[i] = __shfl(v, i);
        if (lane == 0) {
            int bi = 0; double bv = g[0];
            #pragma unroll
            for (int i = 1; i < LTAGS; ++i) if (g[i] > bv) { bv = g[i]; bi = i; }
            sLast = bi;
        }
    } else {
        // ---- alpha boundary scan over 32 chunk matrices (LDS) ----
        const int j = (lane < LTAGS) ? lane : (LTAGS - 1);
        float v = (float)logitsD[(size_t)b * TLEN * LTAGS + j];
        float Mc[LTAGS], Mn[LTAGS];
        #pragma unroll
        for (int i = 0; i < LTAGS; ++i) Mc[i] = sAM[i * LTAGS + j];
        for (int c = 0; c < 32; ++c) {
            if (c < 31) {
                #pragma unroll
                for (int i = 0; i < LTAGS; ++i) Mn[i] = sAM[(c + 1) * 81 + i * LTAGS + j];
            }
            float g[LTAGS];
            #pragma unroll
            for (int i = 0; i < LTAGS; ++i) g[i] = __shfl(v, i);
            float a[LTAGS];
            #pragma unroll
            for (int i = 0; i < LTAGS; ++i) a[i] = g[i] + Mc[i];
            float m = a[0];
            #pragma unroll
            for (int i = 1; i < LTAGS; ++i) m = fmaxf(m, a[i]);
            float sacc = 0.f;
            #pragma unroll
            for (int i = 0; i < LTAGS; ++i) sacc += __expf(a[i] - m);
            v = m + __logf(sacc);
            if (c < 31) {
                #pragma unroll
                for (int i = 0; i < LTAGS; ++i) Mc[i] = Mn[i];
            }
        }
        float g[LTAGS];
        #pragma unroll
        for (int i = 0; i < LTAGS; ++i) g[i] = __shfl(v, i);
        if (lane == 0) {
            float m = g[0];
            #pragma unroll
            for (int i = 1; i < LTAGS; ++i) m = fmaxf(m, g[i]);
            float sacc = 0.f;
            #pragma unroll
            for (int i = 0; i < LTAGS; ++i) sacc += __expf(g[i] - m);
            sDen = (double)(m + __logf(sacc));
        }
    }
    __syncthreads();

    // ---- replay: backpointers + per-chunk composed maps (threads 0..63) ----
    unsigned long long S = IDMAP;
    if (tid < 64) {
        const int c = tid;
        double v[LTAGS];
        #pragma unroll
        for (int j = 0; j < LTAGS; ++j) v[j] = sVstart[c * LTAGS + j];
        const double* lrow = logitsD + ((size_t)b * TLEN + (c * 8 + 1)) * LTAGS;
        double lg[LTAGS], lgN[LTAGS];
        #pragma unroll
        for (int j = 0; j < LTAGS; ++j) lg[j] = lrow[j];

        for (int s = 0; s < 8; ++s) {
            const int t = c * 8 + 1 + s;
            if (s < 7 && t + 1 <= TLEN - 1) {
                const double* ln = lrow + (s + 1) * LTAGS;
                #pragma unroll
                for (int j = 0; j < LTAGS; ++j) lgN[j] = ln[j];
            }
            const bool mk = (sMk[t] != 0);
            unsigned long long pk = 0;
            double nv[LTAGS];
            #pragma unroll
            for (int j = 0; j < LTAGS; ++j) {
                double bst = v[0] + sT64[j];
                int bi = 0;
                #pragma unroll
                for (int k = 1; k < LTAGS; ++k) {
                    double cnd = v[k] + sT64[k * LTAGS + j];
                    bool gt = cnd > bst;
                    bst = gt ? cnd : bst;
                    bi  = gt ? k : bi;
                }
                nv[j] = bst + lg[j];
                pk |= ((unsigned long long)bi) << (4 * j);
            }
            pk = mk ? pk : IDMAP;
            sBPp[t] = pk;
            #pragma unroll
            for (int j = 0; j < LTAGS; ++j) { v[j] = mk ? nv[j] : v[j]; lg[j] = lgN[j]; }
        }
        // compose chunk backtrace map
        unsigned long long G = IDMAP;
        for (int s = 7; s >= 0; --s) {
            const unsigned long long bp = sBPp[c * 8 + 1 + s];
            unsigned long long ng = 0;
            #pragma unroll
            for (int j = 0; j < LTAGS; ++j) {
                int gj = (int)((G >> (4 * j)) & 15);
                int f  = (int)((bp >> (4 * gj)) & 15);
                ng |= ((unsigned long long)f) << (4 * j);
            }
            G = ng;
        }
        S = G;
    }

    // ---- suffix composition scan via shfl: S_c = F_c o ... o F_63 ----
    #pragma unroll
    for (int d = 1; d < 64; d <<= 1) {
        unsigned long long Sn = __shfl_down(S, d);
        if (wave == 0 && lane + d < 64) {
            unsigned long long R = 0;
            #pragma unroll
            for (int x = 0; x < LTAGS; ++x) {
                int y = (int)((Sn >> (4 * x)) & 15);
                int z = (int)((S >> (4 * y)) & 15);
                R |= ((unsigned long long)z) << (4 * x);
            }
            S = R;
        }
    }
    if (tid < 64) {
        const int lt = sLast;
        sTagB[tid] = (int)((S >> (4 * lt)) & 15);
        if (tid == 0) sTagB[64] = lt;
    }
    __syncthreads();

    // ---- chunk-parallel expansion -> predictions ----
    if (tid < 64) {
        const int c = tid;
        int cur = sTagB[c + 1];
        float* po = out + 1 + b * TLEN;
        for (int s = 8; s >= 1; --s) {
            const int t = c * 8 + s;
            if (t < TLEN) {
                int nxt = (int)((sBPp[t] >> (4 * cur)) & 15);
                po[t] = sMk[t - 1] ? (float)nxt : -100.f;
                cur = nxt;
            }
        }
    }
    if (tid == 0) {
        out[1 + b * TLEN] = -100.f;
        wsLoss[b] = sDen - wsNum[b];
        __threadfence();
        sTicket = atomicAdd(wsCnt, 1u);
    }
    __syncthreads();

    // ---- last block: loss reduction (identical shfl tree to old kernel C) ----
    if (sTicket == (BATCH - 1)) {
        __threadfence();
        if (tid < 64) {
            double v = wsLoss[tid];
            #pragma unroll
            for (int off = 32; off > 0; off >>= 1) v += __shfl_down(v, off);
            if (tid == 0) out[0] = (float)v;
        }
    }
}

extern "C" void kernel_launch(void* const* d_in, const int* in_sizes, int n_in,
                              void* d_out, int out_size, void* d_ws, size_t ws_size,
                              hipStream_t stream)
{
    const float* hidden = (const float*)d_in[0];
    const float* W      = (const float*)d_in[1];
    const float* bvec   = (const float*)d_in[2];
    const float* trans  = (const float*)d_in[3];
    const int*   labels = (const int*)d_in[4];
    const int*   att    = (const int*)d_in[5];
    float* out = (float*)d_out;

    char* ws = (char*)d_ws;
    double* logitsD = (double*)(ws + WS_LOGD);
    float*  logitsF = (float*)(ws + WS_LOGF);
    double* wsVM    = (double*)(ws + WS_VM);
    float*  wsAM    = (float*)(ws + WS_AM);
    double* wsNum   = (double*)(ws + WS_NUM);
    double* wsLoss  = (double*)(ws + WS_LOSS);
    unsigned int* wsCnt = (unsigned int*)(ws + WS_CNT);

    logits_kernel<<<512, 256, 0, stream>>>(hidden, W, bvec, logitsD, logitsF, wsCnt);
    chunk_kernel<<<232, 256, 0, stream>>>(trans, labels, att, logitsD, logitsF,
                                          wsVM, wsAM, wsNum);
    crf2_kernel<<<BATCH, 128, 0, stream>>>(trans, labels, att, logitsD,
                                           wsVM, wsAM, wsNum, wsLoss, wsCnt, out);
}